// Round 8
// baseline (163.448 us; speedup 1.0000x reference)
//
#include <hip/hip_runtime.h>

// GraphConv B=256,N=512,D=6,F=128,MAX_DEG=6.
// R13 post-mortem: bytes back to 104MB but dur back to 67us/1.5TB/s ->
// barrier-drain theory DEAD (R12's 2.4TB/s was the scratch traffic itself).
// Only lever that ever moved BW at fixed bytes: INDEPENDENT blocks/CU
// (1->1.5, 2->1.6, 3->3.0, 4->2.3 TB/s). R14: half-molecule blocks, 2/CU.
// Block=(mol,half): summed for own 256 rows as XOR-swizzled 16B granules
// [k0][256][kq^(row&3)] = 64KB exact (no pad), abuf 16KB (full-mol 8-float
// slice; both halves stage it), hist overlaid on summed tail (dead before
// slice-12 writes), rlist overlaid on abuf (post-phase-A). LDS = 81920B
// EXACTLY -> 2 blocks/CU. Halves m and m+256 -> same XCD under round-robin
// -> atoms' 2nd read L2-hot; L3 backstops if mapping differs. Natural-order
// branchy gather (rlist not needed in phase A). Phase B: flattened items,
// B-frags from global Wt (L2-hot), granule-layout A-frags.

typedef short bf16x8 __attribute__((ext_vector_type(8)));
typedef float f32x4  __attribute__((ext_vector_type(4)));
typedef unsigned short ushort_t;
typedef unsigned int uint_t;

constexpr int Nn = 512;
constexpr int Ff = 128;

// ws: Wt bf16 [6][128][128] ([d][n][k])
constexpr size_t WS_NEEDED = 196608;

// Relaxed barrier: publish/consume LDS without draining the global-load queue.
#define BAR_LDS() asm volatile("s_waitcnt lgkmcnt(0)\ns_barrier" ::: "memory")

__device__ inline ushort_t f2bf(float f) {              // round-to-nearest-even
    uint_t u = __float_as_uint(f);
    return (ushort_t)((u + 0x7FFFu + ((u >> 16) & 1u)) >> 16);
}

__device__ inline bool detect_is64(const int* edges32) {
    // int64 edges: odd dwords are sign-extension words in {0,-1}.
    int probe = edges32[2 * (threadIdx.x & 63) + 1];
    return __any(probe > 0) == 0;
}

// ---------------- k0: W fp32 [d][k][n] -> Wt bf16 [d][n][k] ----------------
__global__ __launch_bounds__(1024)
void k0_wt(const float* __restrict__ W, ushort_t* __restrict__ Wt) {
    __shared__ float w[128 * 133];               // 68096 B (pad 133, conflict-free)
    const int d = blockIdx.x;
    const float* src = W + (size_t)d * 16384;
    #pragma unroll
    for (int i = 0; i < 16; i++) {
        int idx = threadIdx.x + i * 1024;        // [k][n] linear, coalesced read
        w[(idx >> 7) * 133 + (idx & 127)] = src[idx];
    }
    __syncthreads();
    ushort_t* dst = Wt + (size_t)d * 16384;
    #pragma unroll
    for (int i = 0; i < 16; i++) {
        int idx = threadIdx.x + i * 1024;        // [n][k] linear, coalesced write
        dst[idx] = f2bf(w[(idx & 127) * 133 + (idx >> 7)]);
    }
}

// ---------------- fused: HALF-molecule per block, 512 threads, 2 blocks/CU ----
// Gather: thread pair (2i,2i+1) owns local row i (natural order), 4 floats
// per slice each. Staging: all 512 threads stage the full molecule's 8-float
// slice (2 float4 each). summed granule g(k0,row,kq)=k0*1024+row*4+(kq^(row&3)).
__global__ __launch_bounds__(512, 4)
void k_fused(const float* __restrict__ atoms,
             const int*   __restrict__ edges32,
             const ushort_t* __restrict__ Wt,
             const float* __restrict__ bias,
             float* __restrict__ out) {
    const int tid  = threadIdx.x;
    const int mol  = blockIdx.x & 255;
    const int half = blockIdx.x >> 8;            // halves m, m+256 -> same XCD (m%8)
    const int r0   = half * 256;                 // own rows [r0, r0+256)
    const bool is64 = detect_is64(edges32);      // convergent

    __shared__ __attribute__((aligned(16))) ushort_t summed[32768];  // 65536 B
    __shared__ float4 abuf4[1024];               // 16384 B; total LDS = 81920 = 160K/2
    int*      hist  = (int*)&summed[32752];      // 24B tail overlay (dead before slice-12 writes)
    ushort_t* rlist = (ushort_t*)abuf4;          // overlay after phase A

    // --- prefetch slices 0,1 into named regs (2 stage-items per thread) ---
    const float4* gsrc = (const float4*)(atoms + (size_t)mol * (Nn * Ff));
    const int pr = tid >> 1, h = tid & 1;        // gather pair coords
    const int arow0 = pr, arow1 = pr + 256;      // stage rows (idx tid, tid+512)
    float4 pfA0 = gsrc[arow0 * 32 + 0 * 2 + h];
    float4 pfA1 = gsrc[arow1 * 32 + 0 * 2 + h];
    float4 pfB0 = gsrc[arow0 * 32 + 1 * 2 + h];
    float4 pfB1 = gsrc[arow1 * 32 + 1 * 2 + h];

    // --- phase 0: edges for own row (both pair threads), degree ranks ---
    if (tid < 6) hist[tid] = 0;
    const int Rg = r0 + pr;                      // own row (global in molecule)
    int er[6];
    if (is64) {                                  // 48B, 16B-aligned
        const uint4* ep = (const uint4*)(edges32 + ((size_t)mol * (Nn * 6) + (size_t)Rg * 6) * 2);
        uint4 q0 = ep[0], q1 = ep[1], q2 = ep[2];
        er[0] = (int)q0.x; er[1] = (int)q0.z;
        er[2] = (int)q1.x; er[3] = (int)q1.z;
        er[4] = (int)q2.x; er[5] = (int)q2.z;
    } else {                                     // 24B, 8B-aligned
        const uint2* ep = (const uint2*)(edges32 + (size_t)mol * (Nn * 6) + (size_t)Rg * 6);
        uint2 q0 = ep[0], q1 = ep[1], q2 = ep[2];
        er[0] = (int)q0.x; er[1] = (int)q0.y;
        er[2] = (int)q1.x; er[3] = (int)q1.y;
        er[4] = (int)q2.x; er[5] = (int)q2.y;
    }
    int deg = 0;
    #pragma unroll
    for (int j = 0; j < 6; j++) deg += (er[j] >= 0) ? 1 : 0;
    if (deg > 5) deg = 5;                        // input spec: deg<=5; guard OOB
    BAR_LDS();                                   // hist zeroed
    int rk = 0;
    if (h == 0) rk = atomicAdd(&hist[deg], 1);
    BAR_LDS();                                   // hist final
    int cnts[6], cbase[6];
    {
        int a = 0;
        #pragma unroll
        for (int d = 0; d < 6; d++) { cnts[d] = hist[d]; cbase[d] = a; a += cnts[d]; }
    }
    // publish slice 0 (consumes pfA*); refill with slice 2.
    // abuf swizzle: granule c of row r at [2r + (c ^ (r&1))].
    abuf4[2 * arow0 + (h ^ (arow0 & 1))] = pfA0;
    abuf4[2 * arow1 + (h ^ (arow1 & 1))] = pfA1;
    pfA0 = gsrc[arow0 * 32 + 2 * 2 + h];
    pfA1 = gsrc[arow1 * 32 + 2 * 2 + h];
    BAR_LDS();                                   // abuf(slice0) ready (hist reads drained too)

    const int selfb = 2 * Rg + (h ^ (Rg & 1));
    const int pubb0 = 2 * arow0 + (h ^ (arow0 & 1));
    const int pubb1 = 2 * arow1 + (h ^ (arow1 & 1));

    // gather one 4-float half-slice; write 8B into swizzled summed granule
#define GATHER(S) do {                                                          \
        float4 a_ = abuf4[selfb];                                               \
        _Pragma("unroll")                                                       \
        for (int j_ = 0; j_ < 6; j_++) {                                        \
            int e_ = er[j_];                                                    \
            if (e_ >= 0) {                                                      \
                float4 v_ = abuf4[2 * e_ + (h ^ (e_ & 1))];                     \
                a_.x += v_.x; a_.y += v_.y; a_.z += v_.z; a_.w += v_.w;         \
            }                                                                   \
        }                                                                       \
        const int g_ = ((S) >> 2) * 1024 + pr * 4 + (((S) & 3) ^ (pr & 3));     \
        uint2 o_;                                                               \
        o_.x = (uint_t)f2bf(a_.x) | ((uint_t)f2bf(a_.y) << 16);                 \
        o_.y = (uint_t)f2bf(a_.z) | ((uint_t)f2bf(a_.w) << 16);                 \
        *(uint2*)&summed[g_ * 8 + h * 4] = o_;                                  \
    } while (0)

    // --- phase A: 16 slices; 2 slices/iter, named pfA*/pfB* (no scratch) ---
    for (int i = 0; i < 8; i++) {
        GATHER(2 * i);                           // even slice
        BAR_LDS();                               // abuf reads done
        abuf4[pubb0] = pfB0;                     // publish slice 2i+1
        abuf4[pubb1] = pfB1;
        if (i < 7) {
            pfB0 = gsrc[arow0 * 32 + (2 * i + 3) * 2 + h];
            pfB1 = gsrc[arow1 * 32 + (2 * i + 3) * 2 + h];
        }
        BAR_LDS();                               // abuf(2i+1) ready
        GATHER(2 * i + 1);                       // odd slice
        if (i < 7) {
            BAR_LDS();
            abuf4[pubb0] = pfA0;                 // publish slice 2i+2
            abuf4[pubb1] = pfA1;
            if (i < 6) {
                pfA0 = gsrc[arow0 * 32 + (2 * i + 4) * 2 + h];
                pfA1 = gsrc[arow1 * 32 + (2 * i + 4) * 2 + h];
            }
            BAR_LDS();                           // abuf(2i+2) ready
        }
    }
#undef GATHER
    BAR_LDS();                                   // summed complete; abuf free
    if (h == 0) rlist[cbase[deg] + rk] = (ushort_t)pr;   // degree-grouped local rows
    BAR_LDS();                                   // rlist visible

    // --- phase B: flattened barrier-free MFMA items over own 256 rows ---
    const int lane = tid & 63, wid = tid >> 6;   // 8 waves
    const int kq = lane >> 4, ml = lane & 15;

    int Tp[7];
    {
        int a = 0;
        #pragma unroll
        for (int d = 0; d < 6; d++) { Tp[d] = a; a += ((cnts[d] + 15) >> 4) * 4; }
        Tp[6] = a;
    }
    const int items = Tp[6];

    for (int it = wid; it < items; it += 8) {
        int d = 0;
        #pragma unroll
        for (int dd = 1; dd < 6; dd++) if (it >= Tp[dd]) d = dd;
        const int loc = it - Tp[d];
        const int ti = loc >> 2, ci = loc & 3;   // row-tile, col-pair
        const int cn = cnts[d], cb = cbase[d];

        int lidx = ti * 16 + ml;
        int cl = (lidx < cn) ? lidx : cn - 1;    // clamp; stores masked
        int row = rlist[cb + cl];                // local row
        bf16x8 af[4];                            // A: m=ml, k=kq*8+k0*32
        #pragma unroll
        for (int k0 = 0; k0 < 4; k0++)
            af[k0] = *(const bf16x8*)&summed[(k0 * 1024 + row * 4 + (kq ^ (row & 3))) * 8];
        int orw[4];                              // C/D rows: kq*4+reg
        #pragma unroll
        for (int r = 0; r < 4; r++) {
            int li = ti * 16 + kq * 4 + r;
            orw[r] = (li < cn) ? (int)rlist[cb + li] : -1;
        }
        const ushort_t* wg = Wt + (size_t)d * 16384;
        #pragma unroll
        for (int n2 = 0; n2 < 2; n2++) {
            const int nt = ci * 2 + n2;
            bf16x8 bfr[4];                       // B: n=ml, k=kq*8+k0*32 (global, L2-hot)
            #pragma unroll
            for (int k0 = 0; k0 < 4; k0++)
                bfr[k0] = *(const bf16x8*)&wg[(nt * 16 + ml) * 128 + k0 * 32 + kq * 8];
            f32x4 c = {0.f, 0.f, 0.f, 0.f};
            #pragma unroll
            for (int k0 = 0; k0 < 4; k0++)
                c = __builtin_amdgcn_mfma_f32_16x16x32_bf16(af[k0], bfr[k0], c, 0, 0, 0);
            const int col = nt * 16 + ml;
            const float bc = bias[d * Ff + col];
            #pragma unroll
            for (int r = 0; r < 4; r++) {
                if (orw[r] >= 0) {
                    float v = c[r] + bc;
                    out[((size_t)mol * Nn + r0 + orw[r]) * Ff + col] = v > 0.f ? v : 0.f;
                }
            }
        }
    }
}

// ---------------- fallback (round-1 kernel) if ws too small ----------------
__global__ __launch_bounds__(128, 2)
void graphconv_fallback(const float* __restrict__ atoms,
                        const int* __restrict__ edges_raw,
                        const float* __restrict__ W,
                        const float* __restrict__ bias,
                        float* __restrict__ out) {
    const int tid = threadIdx.x;
    const int d = blockIdx.x % 6;
    const int k = blockIdx.x / 6;
    const int a0 = k * 256;
    __shared__ int eds[256 * 6];
    __shared__ int list[256];
    __shared__ int cnt;
    __shared__ float sv[2][Ff];
    bool is64;
    { int v = edges_raw[2 * (tid & 63) + 1]; is64 = (__ballot(v > 0) == 0ull); }
    if (!is64) { for (int i = tid; i < 256 * 6; i += 128) eds[i] = edges_raw[a0 * 6 + i]; }
    else       { for (int i = tid; i < 256 * 6; i += 128) eds[i] = edges_raw[2 * (a0 * 6 + i)]; }
    if (tid == 0) cnt = 0;
    __syncthreads();
    for (int i = tid; i < 256; i += 128) {
        int deg = 0;
        #pragma unroll
        for (int j = 0; j < 6; j++) deg += (eds[i * 6 + j] != -1) ? 1 : 0;
        if (deg == d) { int p = atomicAdd(&cnt, 1); list[p] = i; }
    }
    float Wreg[Ff];
    { const float* Wd = W + (size_t)d * Ff * Ff;
      #pragma unroll
      for (int f = 0; f < Ff; f++) Wreg[f] = Wd[f * Ff + tid]; }
    const float breg = bias[d * Ff + tid];
    __syncthreads();
    const int n = cnt;
    const float* batch_atoms = atoms + (size_t)(a0 / Nn) * Nn * Ff;
    const int row0 = a0 % Nn;
    for (int ii = 0; ii < n; ii++) {
        const int i = list[ii];
        float s = batch_atoms[(row0 + i) * Ff + tid];
        #pragma unroll
        for (int j = 0; j < 6; j++) {
            int e = eds[i * 6 + j];
            if (e != -1) s += batch_atoms[e * Ff + tid];
        }
        float* buf = sv[ii & 1];
        buf[tid] = s;
        __syncthreads();
        float acc = breg;
        const float4* sv4 = (const float4*)buf;
        #pragma unroll
        for (int fc = 0; fc < Ff / 4; fc++) {
            float4 x = sv4[fc];
            acc = fmaf(x.x, Wreg[4 * fc + 0], acc);
            acc = fmaf(x.y, Wreg[4 * fc + 1], acc);
            acc = fmaf(x.z, Wreg[4 * fc + 2], acc);
            acc = fmaf(x.w, Wreg[4 * fc + 3], acc);
        }
        out[(size_t)(a0 + i) * Ff + tid] = fmaxf(acc, 0.0f);
    }
}

extern "C" void kernel_launch(void* const* d_in, const int* in_sizes, int n_in,
                              void* d_out, int out_size, void* d_ws, size_t ws_size,
                              hipStream_t stream) {
    const float* atoms = (const float*)d_in[0];
    const int*   edges = (const int*)d_in[1];
    const float* W     = (const float*)d_in[2];
    const float* bias  = (const float*)d_in[3];
    float*       outp  = (float*)d_out;

    if (ws_size >= WS_NEEDED) {
        ushort_t* Wt = (ushort_t*)d_ws;
        k0_wt<<<6, 1024, 0, stream>>>(W, Wt);
        k_fused<<<512, 512, 0, stream>>>(atoms, edges, Wt, bias, outp);
    } else {
        graphconv_fallback<<<3072, 128, 0, stream>>>(atoms, edges, W, bias, outp);
    }
}